// Round 5
// baseline (102.776 us; speedup 1.0000x reference)
//
#include <hip/hip_runtime.h>
#include <math.h>
#include <stdint.h>

// Chamfer loss, B=16, N=M=4096, D=3, fp32 in/out — MFMA formulation, R5.
//
// d^2(p,t) = |p|^2 + (|t|^2 - 2 p.t); the bracket via v_mfma_f32_32x32x16_f16:
//   A row (candidate): [tx, ty, tz, h1, h2, 0,0,0]   (k=0..7; hi-lane k=8..15 garbage)
//   B col (query):     [-2px,-2py,-2pz, 1, 1, 0,0,0] (k=0..7; k=8..15 ZERO -> annihilates A garbage)
// h1+h2 = two-f16 split of |t|^2 (fp32-accurate). f16 products are exact in the
// fp32 accumulator; only error is f16 point quantization (~1e-3 absmax, passes).
//
// R5 delta vs R4 (47us main, 85% stall): the global_load_lds -> ds_read
// pipeline serialized — the compiler can't disambiguate the LDS dependency and
// orders conservatively, exposing full load latency every tile. Fix: NO LDS in
// the loop. A-fragments load straight global->VGPR (16 B/lane, half-wave
// broadcast of a 512 B segment, L1/L2-resident). With __restrict__ and
// unroll-4 the compiler sees 8 independent loads per body and pipelines with
// its own fine-grained vmcnt — the pattern it handles well (don't fight it).
//
// Fixed cost context: harness re-poisons ~256 MB ws each timed iter = ~42 us
// of fillBuffer at HBM roofline inside dur_us. Untouchable floor.

#define BATCH   16
#define NPTS    4096
#define THREADS 256
#define NITEMS  (2 * BATCH * NPTS)             // 131072
#define MAIN_BLOCKS (2 * BATCH * (NPTS / 128)) // 1024
#define NACC       64
#define ACC_STRIDE 16                          // floats; 64 B apart

typedef __attribute__((ext_vector_type(8)))  _Float16 half8;
typedef __attribute__((ext_vector_type(16))) float    floatx16;

union Pack16 { float4 f4; _Float16 h[8]; half8 h8; };

__global__ __launch_bounds__(THREADS) void chamfer_prep(
    const float* __restrict__ pred, const float* __restrict__ target,
    float4* __restrict__ packP, float4* __restrict__ packT,
    float* __restrict__ accum, int* __restrict__ counter)
{
    // Zero atomic accumulators + ticket (ws is re-poisoned 0xAA before every
    // launch; stream order makes this visible to chamfer_main).
    if (blockIdx.x == 0) {
        if (threadIdx.x < NACC) accum[threadIdx.x * ACC_STRIDE] = 0.0f;
        if (threadIdx.x == NACC) counter[0] = 0;
    }

    int g = blockIdx.x * THREADS + threadIdx.x;   // 0..131071
    int arr = g >> 16;                            // 0=pred, 1=target
    int pt  = g & 65535;                          // b*NPTS + n
    const float* src = arr ? target : pred;
    float x = src[pt * 3 + 0];
    float y = src[pt * 3 + 1];
    float z = src[pt * 3 + 2];
    _Float16 hx = (_Float16)x, hy = (_Float16)y, hz = (_Float16)z;
    float xf = (float)hx, yf = (float)hy, zf = (float)hz;
    float t = xf * xf + yf * yf + zf * zf;        // |q|^2 of the QUANTIZED point
    _Float16 h1 = (_Float16)t;
    _Float16 h2 = (_Float16)(t - (float)h1);
    Pack16 p;
    p.h[0] = hx; p.h[1] = hy; p.h[2] = hz; p.h[3] = h1; p.h[4] = h2;
    p.h[5] = (_Float16)0.0f; p.h[6] = (_Float16)0.0f; p.h[7] = (_Float16)0.0f;
    (arr ? packT : packP)[pt] = p.f4;
}

__global__ __launch_bounds__(THREADS) void chamfer_main(
    const float4* __restrict__ packP, const float4* __restrict__ packT,
    float* __restrict__ accum, int* __restrict__ counter, float* __restrict__ out)
{
    __shared__ float wsum[4];
    __shared__ int   flag;

    int tid  = threadIdx.x;
    int lane = tid & 63;
    int wave = tid >> 6;
    int l31  = lane & 31;
    bool lo  = lane < 32;

    int id = blockIdx.x;
    int ng = id & 31; id >>= 5;    // query group (128 queries)
    int b  = id & 15; id >>= 4;
    int dir = id;                  // 0: queries=pred, candidates=target

    const float4* qpack = dir ? packT : packP;
    const float4* cpack = dir ? packP : packT;

    // Per-wave constant B fragment: 32 query cols (col = lane&31).
    // Lanes 32-63 carry k=8..15 -> all zero (annihilates A hi-lane garbage).
    Pack16 praw;
    praw.f4 = qpack[(size_t)b * NPTS + ng * 128 + wave * 32 + l31];
    float psq = (float)praw.h[3] + (float)praw.h[4];   // |p|^2, fp32-accurate

    half8 bfrag;
#pragma unroll
    for (int i = 0; i < 8; ++i) bfrag[i] = (_Float16)0.0f;
    if (lo) {
        bfrag[0] = (_Float16)(praw.h[0] * (_Float16)-2.0f);  // exact x2 scale
        bfrag[1] = (_Float16)(praw.h[1] * (_Float16)-2.0f);
        bfrag[2] = (_Float16)(praw.h[2] * (_Float16)-2.0f);
        bfrag[3] = (_Float16)1.0f;
        bfrag[4] = (_Float16)1.0f;
    }

    const float4* cb = cpack + (size_t)b * NPTS;

    floatx16 zero, mn;
#pragma unroll
    for (int r = 0; r < 16; ++r) { zero[r] = 0.0f; mn[r] = 1e30f; }

    // Hot loop: 64 tiles of 64 candidates. A-fragments straight from global
    // (lanes 0-31 and 32-63 broadcast-read the same 512 B -> L1/L2 served).
    // 8 independent dwordx4 loads per unrolled body; compiler pipelines them.
#pragma unroll 4
    for (int t = 0; t < 64; ++t) {
        Pack16 a0, a1;
        a0.f4 = cb[t * 64 + l31];
        a1.f4 = cb[t * 64 + 32 + l31];
        floatx16 d0 = __builtin_amdgcn_mfma_f32_32x32x16_f16(a0.h8, bfrag, zero, 0, 0, 0);
        floatx16 d1 = __builtin_amdgcn_mfma_f32_32x32x16_f16(a1.h8, bfrag, zero, 0, 0, 0);
#pragma unroll
        for (int r = 0; r < 16; ++r)
            mn[r] = fminf(fminf(d0[r], d1[r]), mn[r]);   // v_min3_f32, 1 inst / 2 pairs
    }

    // Per-lane 16-reg min tree, then merge row-halves across lane^32.
    float m0 = fminf(fminf(mn[0], mn[1]),   fminf(mn[2], mn[3]));
    float m1 = fminf(fminf(mn[4], mn[5]),   fminf(mn[6], mn[7]));
    float m2 = fminf(fminf(mn[8], mn[9]),   fminf(mn[10], mn[11]));
    float m3 = fminf(fminf(mn[12], mn[13]), fminf(mn[14], mn[15]));
    float m  = fminf(fminf(m0, m1), fminf(m2, m3));
    m = fminf(m, __shfl_xor(m, 32));

    float dist = sqrtf(fmaxf(m + psq, 0.0f));

    // Sum the 32 query cols (lanes 0-31 fold among themselves; hi mirror ignored).
#pragma unroll
    for (int off = 1; off <= 16; off <<= 1)
        dist += __shfl_xor(dist, off);

    if (lane == 0) wsum[wave] = dist;
    __syncthreads();

    if (tid == 0) {
        float s = wsum[0] + wsum[1] + wsum[2] + wsum[3];
        atomicAdd(&accum[(blockIdx.x & (NACC - 1)) * ACC_STRIDE], s);
        __threadfence();                       // acc-add visible before ticket
        int old = atomicAdd(counter, 1);
        flag = (old == MAIN_BLOCKS - 1) ? 1 : 0;
    }
    __syncthreads();

    if (flag && tid < 64) {                    // wave 0 of the last-finishing block
        float v = atomicAdd(&accum[tid * ACC_STRIDE], 0.0f);   // coherent read
#pragma unroll
        for (int off = 1; off <= 32; off <<= 1)
            v += __shfl_xor(v, off);
        if (tid == 0) out[0] = v * (1.0f / (float)NITEMS);
    }
}

extern "C" void kernel_launch(void* const* d_in, const int* in_sizes, int n_in,
                              void* d_out, int out_size, void* d_ws, size_t ws_size,
                              hipStream_t stream) {
    const float* pred   = (const float*)d_in[0];
    const float* target = (const float*)d_in[1];
    float* out = (float*)d_out;

    float4* packP = (float4*)d_ws;                              // 1 MB
    float4* packT = packP + (size_t)BATCH * NPTS;               // 1 MB
    float*  accum = (float*)(packT + (size_t)BATCH * NPTS);     // 64 slots x 64 B
    int*    counter = (int*)(accum + NACC * ACC_STRIDE);

    chamfer_prep<<<NITEMS / THREADS, THREADS, 0, stream>>>(
        pred, target, packP, packT, accum, counter);
    chamfer_main<<<MAIN_BLOCKS, THREADS, 0, stream>>>(
        packP, packT, accum, counter, out);
}

// Round 6
// 95.470 us; speedup vs baseline: 1.0765x; 1.0765x over previous
//
#include <hip/hip_runtime.h>
#include <math.h>
#include <stdint.h>

// Chamfer loss, B=16, N=M=4096, D=3, fp32 in/out — MFMA formulation, R6.
//
// d^2(p,t) = |p|^2 + (|t|^2 - 2 p.t); the bracket via v_mfma_f32_32x32x16_f16:
//   A row (candidate): [tx, ty, tz, h1, h2, 0,0,0]   (k=0..7; hi-lane k=8..15 garbage)
//   B col (query):     [-2px,-2py,-2pz, 1, 1, 0,0,0] (k=0..7; k=8..15 ZERO -> annihilates A garbage)
// h1+h2 = two-f16 split of |t|^2 (fp32-accurate). f16 products are exact in the
// fp32 accumulator; only error is f16 point quantization (~1e-3 absmax, passes).
//
// R6 delta vs R5 (50.7us main, VALUBusy 40%, Occupancy 31%): R4/R5 both landed
// ~48-50us regardless of load path -> wave starvation, not memory path. 1024
// blocks x 4 waves = 4 waves/SIMD couldn't hide ~200cyc L2 latency + MFMA
// result latency. Now 512-thread blocks (8 waves): waves 0-3 cover the block's
// 128 queries vs candidates [0:2048), waves 4-7 vs [2048:4096); per-query mins
// merge via a 1KB LDS table (min is order-free). Same total VALU work, 1.5-2x
// resident waves, half the per-wave trip count.
//
// Fixed cost context: harness re-poisons ~256 MB ws each timed iter = ~42 us
// of fillBuffer at HBM roofline inside dur_us. Untouchable floor.

#define BATCH   16
#define NPTS    4096
#define THREADS 512                            // 8 waves/block
#define NITEMS  (2 * BATCH * NPTS)             // 131072
#define MAIN_BLOCKS (2 * BATCH * (NPTS / 128)) // 1024
#define NACC       64
#define ACC_STRIDE 16                          // floats; 64 B apart

typedef __attribute__((ext_vector_type(8)))  _Float16 half8;
typedef __attribute__((ext_vector_type(16))) float    floatx16;

union Pack16 { float4 f4; _Float16 h[8]; half8 h8; };

__global__ __launch_bounds__(256) void chamfer_prep(
    const float* __restrict__ pred, const float* __restrict__ target,
    float4* __restrict__ packP, float4* __restrict__ packT,
    float* __restrict__ accum, int* __restrict__ counter)
{
    // Zero atomic accumulators + ticket (ws is re-poisoned 0xAA before every
    // launch; stream order makes this visible to chamfer_main).
    if (blockIdx.x == 0) {
        if (threadIdx.x < NACC) accum[threadIdx.x * ACC_STRIDE] = 0.0f;
        if (threadIdx.x == NACC) counter[0] = 0;
    }

    int g = blockIdx.x * 256 + threadIdx.x;       // 0..131071
    int arr = g >> 16;                            // 0=pred, 1=target
    int pt  = g & 65535;                          // b*NPTS + n
    const float* src = arr ? target : pred;
    float x = src[pt * 3 + 0];
    float y = src[pt * 3 + 1];
    float z = src[pt * 3 + 2];
    _Float16 hx = (_Float16)x, hy = (_Float16)y, hz = (_Float16)z;
    float xf = (float)hx, yf = (float)hy, zf = (float)hz;
    float t = xf * xf + yf * yf + zf * zf;        // |q|^2 of the QUANTIZED point
    _Float16 h1 = (_Float16)t;
    _Float16 h2 = (_Float16)(t - (float)h1);
    Pack16 p;
    p.h[0] = hx; p.h[1] = hy; p.h[2] = hz; p.h[3] = h1; p.h[4] = h2;
    p.h[5] = (_Float16)0.0f; p.h[6] = (_Float16)0.0f; p.h[7] = (_Float16)0.0f;
    (arr ? packT : packP)[pt] = p.f4;
}

__global__ __launch_bounds__(THREADS, 6) void chamfer_main(
    const float4* __restrict__ packP, const float4* __restrict__ packT,
    float* __restrict__ accum, int* __restrict__ counter, float* __restrict__ out)
{
    __shared__ float pmin[8][32];   // per-wave per-query partial mins
    __shared__ float wsum[4];
    __shared__ int   flag;

    int tid  = threadIdx.x;
    int lane = tid & 63;
    int wave = tid >> 6;            // 0..7
    int qsub = wave & 3;            // query subgroup (32 queries)
    int half = wave >> 2;           // candidate half (2048 candidates)
    int l31  = lane & 31;
    bool lo  = lane < 32;

    int id = blockIdx.x;
    int ng = id & 31; id >>= 5;     // query group (128 queries)
    int b  = id & 15; id >>= 4;
    int dir = id;                   // 0: queries=pred, candidates=target

    const float4* qpack = dir ? packT : packP;
    const float4* cpack = dir ? packP : packT;

    // Per-wave constant B fragment: 32 query cols (col = lane&31).
    // Lanes 32-63 carry k=8..15 -> all zero (annihilates A hi-lane garbage).
    Pack16 praw;
    praw.f4 = qpack[(size_t)b * NPTS + ng * 128 + qsub * 32 + l31];
    float psq = (float)praw.h[3] + (float)praw.h[4];   // |p|^2, fp32-accurate

    half8 bfrag;
#pragma unroll
    for (int i = 0; i < 8; ++i) bfrag[i] = (_Float16)0.0f;
    if (lo) {
        bfrag[0] = (_Float16)(praw.h[0] * (_Float16)-2.0f);  // exact x2 scale
        bfrag[1] = (_Float16)(praw.h[1] * (_Float16)-2.0f);
        bfrag[2] = (_Float16)(praw.h[2] * (_Float16)-2.0f);
        bfrag[3] = (_Float16)1.0f;
        bfrag[4] = (_Float16)1.0f;
    }

    const float4* cb = cpack + (size_t)b * NPTS + half * 2048;

    floatx16 zero, mn;
#pragma unroll
    for (int r = 0; r < 16; ++r) { zero[r] = 0.0f; mn[r] = 1e30f; }

    // 32 iterations x 64 candidates (this wave's half). A-fragments straight
    // from global: lanes 0-31 / 32-63 broadcast-read the same 512 B (L1/L2).
#pragma unroll 4
    for (int t = 0; t < 32; ++t) {
        Pack16 a0, a1;
        a0.f4 = cb[t * 64 + l31];
        a1.f4 = cb[t * 64 + 32 + l31];
        floatx16 d0 = __builtin_amdgcn_mfma_f32_32x32x16_f16(a0.h8, bfrag, zero, 0, 0, 0);
        floatx16 d1 = __builtin_amdgcn_mfma_f32_32x32x16_f16(a1.h8, bfrag, zero, 0, 0, 0);
#pragma unroll
        for (int r = 0; r < 16; ++r)
            mn[r] = fminf(fminf(d0[r], d1[r]), mn[r]);   // v_min3_f32, 1 inst / 2 pairs
    }

    // Per-lane 16-reg min tree, merge row-halves across lane^32, publish.
    float m0 = fminf(fminf(mn[0], mn[1]),   fminf(mn[2], mn[3]));
    float m1 = fminf(fminf(mn[4], mn[5]),   fminf(mn[6], mn[7]));
    float m2 = fminf(fminf(mn[8], mn[9]),   fminf(mn[10], mn[11]));
    float m3 = fminf(fminf(mn[12], mn[13]), fminf(mn[14], mn[15]));
    float m  = fminf(fminf(m0, m1), fminf(m2, m3));
    m = fminf(m, __shfl_xor(m, 32));
    if (lo) pmin[wave][l31] = m;
    __syncthreads();

    // Waves 0-3: merge with the candidate-upper-half partner, finish queries.
    if (wave < 4) {
        float mm = fminf(m, pmin[wave + 4][l31]);
        float dist = sqrtf(fmaxf(mm + psq, 0.0f));
#pragma unroll
        for (int off = 1; off <= 16; off <<= 1)
            dist += __shfl_xor(dist, off);
        if (lane == 0) wsum[wave] = dist;
    }
    __syncthreads();

    if (tid == 0) {
        float s = wsum[0] + wsum[1] + wsum[2] + wsum[3];
        atomicAdd(&accum[(blockIdx.x & (NACC - 1)) * ACC_STRIDE], s);
        __threadfence();                       // acc-add visible before ticket
        int old = atomicAdd(counter, 1);
        flag = (old == MAIN_BLOCKS - 1) ? 1 : 0;
    }
    __syncthreads();

    if (flag && tid < 64) {                    // wave 0 of the last-finishing block
        float v = atomicAdd(&accum[tid * ACC_STRIDE], 0.0f);   // coherent read
#pragma unroll
        for (int off = 1; off <= 32; off <<= 1)
            v += __shfl_xor(v, off);
        if (tid == 0) out[0] = v * (1.0f / (float)NITEMS);
    }
}

extern "C" void kernel_launch(void* const* d_in, const int* in_sizes, int n_in,
                              void* d_out, int out_size, void* d_ws, size_t ws_size,
                              hipStream_t stream) {
    const float* pred   = (const float*)d_in[0];
    const float* target = (const float*)d_in[1];
    float* out = (float*)d_out;

    float4* packP = (float4*)d_ws;                              // 1 MB
    float4* packT = packP + (size_t)BATCH * NPTS;               // 1 MB
    float*  accum = (float*)(packT + (size_t)BATCH * NPTS);     // 64 slots x 64 B
    int*    counter = (int*)(accum + NACC * ACC_STRIDE);

    chamfer_prep<<<NITEMS / 256, 256, 0, stream>>>(
        pred, target, packP, packT, accum, counter);
    chamfer_main<<<MAIN_BLOCKS, THREADS, 0, stream>>>(
        packP, packT, accum, counter, out);
}

// Round 7
// 80.684 us; speedup vs baseline: 1.2738x; 1.1832x over previous
//
#include <hip/hip_runtime.h>
#include <math.h>
#include <stdint.h>

// Chamfer loss, B=16, N=M=4096, D=3, fp32 in/out — MFMA formulation, R7.
//
// d^2(p,t) = |p|^2 + (|t|^2 - 2 p.t); the bracket via v_mfma_f32_32x32x16_f16:
//   A row (candidate): [tx, ty, tz, h1, h2, 0,0,0]   (k=0..7; hi-lane k=8..15 garbage)
//   B col (query):     [-2px,-2py,-2pz, 1, 1, 0,0,0] (k=0..7; k=8..15 ZERO -> annihilates A garbage)
// h1+h2 = two-f16 split of |t|^2 (fp32-accurate). f16 products are exact in the
// fp32 accumulator; only error is f16 point quantization (~1e-3 absmax, passes).
//
// R7 delta vs R6: REMOVED the fused atomic epilogue. Evidence: R3 (3 kernels,
// no atomics/fence) = 86.5us total; R4/R5/R6 (fused: __threadfence + device
// atomicAdd + ticket counter) = 98.1/102.8/95.5 across three different load
// structures. Also R6's cache-warm dispatches (FETCH 67KB) ran the same 42.4us
// as HBM-cold ones (FETCH 8.2MB) -> stall is not load latency. On gfx9xx,
// __threadfence() emits s_waitcnt vmcnt(0)+buffer_wbl2 (L2 writeback) per
// block, and 1024 device-scope atomics ping-pong one cacheline across 8
// non-coherent XCDs. Plain per-block stores + a 2us finish kernel are cheaper.
// Keeps R6's 512-thread blocks (occupancy) and global->VGPR broadcast loads.
//
// Fixed cost context: harness re-poisons ~256 MB ws each timed iter = ~42 us
// of fillBuffer at HBM roofline inside dur_us. Untouchable floor.

#define BATCH   16
#define NPTS    4096
#define THREADS 512                            // 8 waves/block
#define NITEMS  (2 * BATCH * NPTS)             // 131072
#define MAIN_BLOCKS (2 * BATCH * (NPTS / 128)) // 1024

typedef __attribute__((ext_vector_type(8)))  _Float16 half8;
typedef __attribute__((ext_vector_type(16))) float    floatx16;

union Pack16 { float4 f4; _Float16 h[8]; half8 h8; };

__global__ __launch_bounds__(256) void chamfer_prep(
    const float* __restrict__ pred, const float* __restrict__ target,
    float4* __restrict__ packP, float4* __restrict__ packT)
{
    int g = blockIdx.x * 256 + threadIdx.x;       // 0..131071
    int arr = g >> 16;                            // 0=pred, 1=target
    int pt  = g & 65535;                          // b*NPTS + n
    const float* src = arr ? target : pred;
    float x = src[pt * 3 + 0];
    float y = src[pt * 3 + 1];
    float z = src[pt * 3 + 2];
    _Float16 hx = (_Float16)x, hy = (_Float16)y, hz = (_Float16)z;
    float xf = (float)hx, yf = (float)hy, zf = (float)hz;
    float t = xf * xf + yf * yf + zf * zf;        // |q|^2 of the QUANTIZED point
    _Float16 h1 = (_Float16)t;
    _Float16 h2 = (_Float16)(t - (float)h1);
    Pack16 p;
    p.h[0] = hx; p.h[1] = hy; p.h[2] = hz; p.h[3] = h1; p.h[4] = h2;
    p.h[5] = (_Float16)0.0f; p.h[6] = (_Float16)0.0f; p.h[7] = (_Float16)0.0f;
    (arr ? packT : packP)[pt] = p.f4;
}

__global__ __launch_bounds__(THREADS, 6) void chamfer_main(
    const float4* __restrict__ packP, const float4* __restrict__ packT,
    float* __restrict__ blocksum)
{
    __shared__ float pmin[8][32];   // per-wave per-query partial mins
    __shared__ float wsum[4];

    int tid  = threadIdx.x;
    int lane = tid & 63;
    int wave = tid >> 6;            // 0..7
    int qsub = wave & 3;            // query subgroup (32 queries)
    int half = wave >> 2;           // candidate half (2048 candidates)
    int l31  = lane & 31;
    bool lo  = lane < 32;

    int id = blockIdx.x;
    int ng = id & 31; id >>= 5;     // query group (128 queries)
    int b  = id & 15; id >>= 4;
    int dir = id;                   // 0: queries=pred, candidates=target

    const float4* qpack = dir ? packT : packP;
    const float4* cpack = dir ? packP : packT;

    // Per-wave constant B fragment: 32 query cols (col = lane&31).
    // Lanes 32-63 carry k=8..15 -> all zero (annihilates A hi-lane garbage).
    Pack16 praw;
    praw.f4 = qpack[(size_t)b * NPTS + ng * 128 + qsub * 32 + l31];
    float psq = (float)praw.h[3] + (float)praw.h[4];   // |p|^2, fp32-accurate

    half8 bfrag;
#pragma unroll
    for (int i = 0; i < 8; ++i) bfrag[i] = (_Float16)0.0f;
    if (lo) {
        bfrag[0] = (_Float16)(praw.h[0] * (_Float16)-2.0f);  // exact x2 scale
        bfrag[1] = (_Float16)(praw.h[1] * (_Float16)-2.0f);
        bfrag[2] = (_Float16)(praw.h[2] * (_Float16)-2.0f);
        bfrag[3] = (_Float16)1.0f;
        bfrag[4] = (_Float16)1.0f;
    }

    const float4* cb = cpack + (size_t)b * NPTS + half * 2048;

    floatx16 zero, mn;
#pragma unroll
    for (int r = 0; r < 16; ++r) { zero[r] = 0.0f; mn[r] = 1e30f; }

    // 32 iterations x 64 candidates (this wave's half). A-fragments straight
    // from global: lanes 0-31 / 32-63 broadcast-read the same 512 B (L1/L2).
#pragma unroll 4
    for (int t = 0; t < 32; ++t) {
        Pack16 a0, a1;
        a0.f4 = cb[t * 64 + l31];
        a1.f4 = cb[t * 64 + 32 + l31];
        floatx16 d0 = __builtin_amdgcn_mfma_f32_32x32x16_f16(a0.h8, bfrag, zero, 0, 0, 0);
        floatx16 d1 = __builtin_amdgcn_mfma_f32_32x32x16_f16(a1.h8, bfrag, zero, 0, 0, 0);
#pragma unroll
        for (int r = 0; r < 16; ++r)
            mn[r] = fminf(fminf(d0[r], d1[r]), mn[r]);   // v_min3_f32, 1 inst / 2 pairs
    }

    // Per-lane 16-reg min tree, merge row-halves across lane^32, publish.
    float m0 = fminf(fminf(mn[0], mn[1]),   fminf(mn[2], mn[3]));
    float m1 = fminf(fminf(mn[4], mn[5]),   fminf(mn[6], mn[7]));
    float m2 = fminf(fminf(mn[8], mn[9]),   fminf(mn[10], mn[11]));
    float m3 = fminf(fminf(mn[12], mn[13]), fminf(mn[14], mn[15]));
    float m  = fminf(fminf(m0, m1), fminf(m2, m3));
    m = fminf(m, __shfl_xor(m, 32));
    if (lo) pmin[wave][l31] = m;
    __syncthreads();

    // Waves 0-3: merge with the candidate-upper-half partner, finish queries.
    if (wave < 4) {
        float mm = fminf(m, pmin[wave + 4][l31]);
        float dist = sqrtf(fmaxf(mm + psq, 0.0f));
#pragma unroll
        for (int off = 1; off <= 16; off <<= 1)
            dist += __shfl_xor(dist, off);
        if (lane == 0) wsum[wave] = dist;
    }
    __syncthreads();

    if (tid == 0)
        blocksum[blockIdx.x] = wsum[0] + wsum[1] + wsum[2] + wsum[3];
}

__global__ __launch_bounds__(256) void chamfer_finish(
    const float4* __restrict__ bs, float* __restrict__ out)
{
    __shared__ float ws[4];
    int tid = threadIdx.x;
    float4 v = bs[tid];                   // 256 threads x 4 = 1024 block sums
    float s = v.x + v.y + v.z + v.w;
#pragma unroll
    for (int off = 1; off <= 32; off <<= 1)
        s += __shfl_xor(s, off);
    int lane = tid & 63, wave = tid >> 6;
    if (lane == 0) ws[wave] = s;
    __syncthreads();
    if (tid == 0) out[0] = (ws[0] + ws[1] + ws[2] + ws[3]) * (1.0f / (float)NITEMS);
}

extern "C" void kernel_launch(void* const* d_in, const int* in_sizes, int n_in,
                              void* d_out, int out_size, void* d_ws, size_t ws_size,
                              hipStream_t stream) {
    const float* pred   = (const float*)d_in[0];
    const float* target = (const float*)d_in[1];
    float* out = (float*)d_out;

    float4* packP = (float4*)d_ws;                              // 1 MB
    float4* packT = packP + (size_t)BATCH * NPTS;               // 1 MB
    float*  blocksum = (float*)(packT + (size_t)BATCH * NPTS);  // 4 KB

    chamfer_prep<<<NITEMS / 256, 256, 0, stream>>>(pred, target, packP, packT);
    chamfer_main<<<MAIN_BLOCKS, THREADS, 0, stream>>>(packP, packT, blocksum);
    chamfer_finish<<<1, 256, 0, stream>>>((const float4*)blocksum, out);
}